// Round 15
// baseline (243.705 us; speedup 1.0000x reference)
//
#include <hip/hip_runtime.h>
#include <hip/hip_bf16.h>
#include <hip/hip_fp16.h>

#define N_USER 100000
#define N_ITEM 100000
#define EMB_DIM 64
#define NEG_SLOPE 0.2f

#define SHIFT 6              // 64 fine dst per coarse bucket
#define FPB 64               // 1 << SHIFT
#define FMASK 63
#define NB 1563              // ceil(100000 / 64), same for both sides
#define GCAP 1024            // fixed slot capacity per bucket (avg 640, +15 sigma)
#define BIN_TILE 16384       // 16K-edge tiles: halves cur-atomic contention

struct Side {
    const float*  srcf;   // fp32 src table
    const __half* srch;   // fp16 src table (fp16 tier only)
    const float*  dstf;   // fp32 dst table
    const __half* dsth;   // fp16 dst table (fp16 tier only; = other half-table)
    const int*    src;
    const int*    dst;
    int           E;
    int           n_dst;
    int*          cur;    // [NB] atomic cursors (init 0; final value = count)
    int*          pairs;  // [NB*GCAP] packed (src<<SHIFT)|fine, fixed-stride
    float*        out;    // [n_dst, EMB_DIM]
};

// ---- DPP 16-lane all-reduce: x += row_ror<N>(x), N=1,2,4,8 (VALU pipe). ----
template <int CTRL>
__device__ __forceinline__ float dpp_add(float x) {
    int v = __builtin_amdgcn_update_dpp(0, __float_as_int(x), CTRL, 0xf, 0xf, true);
    return x + __int_as_float(v);
}
__device__ __forceinline__ float row16_allsum(float p) {
    p = dpp_add<0x121>(p);
    p = dpp_add<0x122>(p);
    p = dpp_add<0x124>(p);
    p = dpp_add<0x128>(p);
    return p;
}

// Raw (unconverted) gather payload: uint2 for fp16 rows, float4 for fp32.
template <bool H> struct RawT;
template <> struct RawT<true>  { using type = uint2;  };
template <> struct RawT<false> { using type = float4; };

template <bool H>
__device__ __forceinline__ typename RawT<H>::type
raw_load(const Side& S, int si, int sub) {
    if constexpr (H) {
        return *reinterpret_cast<const uint2*>(S.srch + (size_t)si * EMB_DIM + sub * 4);
    } else {
        return *reinterpret_cast<const float4*>(S.srcf + (size_t)si * EMB_DIM + sub * 4);
    }
}
template <bool H>
__device__ __forceinline__ float4 to_f4(typename RawT<H>::type v) {
    if constexpr (H) {
        __half2 h0 = *reinterpret_cast<const __half2*>(&v.x);
        __half2 h1 = *reinterpret_cast<const __half2*>(&v.y);
        float2 f0 = __half22float2(h0), f1 = __half22float2(h1);
        return make_float4(f0.x, f0.y, f1.x, f1.y);
    } else {
        return v;
    }
}
template <bool H>
__device__ __forceinline__ float4 load_dst(const Side& S, int d, int sub) {
    if constexpr (H) {
        uint2 v = *reinterpret_cast<const uint2*>(S.dsth + (size_t)d * EMB_DIM + sub * 4);
        return to_f4<true>(v);
    } else {
        return *reinterpret_cast<const float4*>(S.dstf + (size_t)d * EMB_DIM + sub * 4);
    }
}

// ---------- 1. fused prep: fixed-stride bin tiles ∥ fp16 convert ------------
__global__ void prep_kernel(Side A, Side B, int nbinA, int nbinB,
                            const float* tu, const float* ti,
                            __half* hu, __half* hi) {
    int b = blockIdx.x;
    if (b < nbinA + nbinB) {
        __shared__ int h[NB];   // per-tile histogram, then local cursor
        __shared__ int bl[NB];  // per-tile base reservation
        Side S; int lb;
        if (b < nbinA) { S = A; lb = b; }
        else           { S = B; lb = b - nbinA; }
        int t = threadIdx.x;
        for (int i = t; i < NB; i += blockDim.x) h[i] = 0;
        __syncthreads();
        int beg = lb * BIN_TILE;
        int end = min(beg + BIN_TILE, S.E);
        for (int i = beg + t; i < end; i += blockDim.x)
            atomicAdd(&h[S.dst[i] >> SHIFT], 1);
        __syncthreads();
        for (int i = t; i < NB; i += blockDim.x) {
            int c = h[i];
            bl[i] = c ? atomicAdd(&S.cur[i], c) : 0;
            h[i] = 0;  // reuse as local cursor
        }
        __syncthreads();
        for (int i = beg + t; i < end; i += blockDim.x) {
            int d = S.dst[i];
            int bk = d >> SHIFT;
            int r = bl[bk] + atomicAdd(&h[bk], 1);
            if (r < GCAP)  // overflow guard (never hit for random input)
                S.pairs[(size_t)bk * GCAP + r] = (S.src[i] << SHIFT) | (d & FMASK);
        }
    } else if (tu != nullptr) {
        const long n4 = (long)N_USER * EMB_DIM / 4;   // float4s per table
        long i = (long)(b - nbinA - nbinB) * blockDim.x + threadIdx.x;
        const float4* s; uint2* d; long j;
        if (i < n4) { s = (const float4*)tu; d = (uint2*)hu; j = i; }
        else        { s = (const float4*)ti; d = (uint2*)hi; j = i - n4; }
        if (j < n4) {
            float4 v = s[j];
            __half2 p0 = __floats2half2_rn(v.x, v.y);
            __half2 p1 = __floats2half2_rn(v.z, v.w);
            uint2 o;
            o.x = *reinterpret_cast<unsigned int*>(&p0);
            o.y = *reinterpret_cast<unsigned int*>(&p1);
            d[j] = o;
        }
    }
}

// ---------- 2. per-bucket fine sort (LDS) + balanced dual-chain softmax -----
// One block per coarse bucket; 2 chains x 2 passes, degree-rank snake balance.
// Distance-8 DOUBLE buffer (two named sets, widened from R12's 4; R13's
// triple-set rotation spilled to scratch — WRITE 50->132 MB — the 2-set copy
// pattern is what the compiler promotes). dst rows from fp16 half-tables.
// __launch_bounds__(256, 6): A/B-measured — 8 blocks/CU thrashes per-XCD L2.
template <bool H>
__global__ void __launch_bounds__(256, 6) gat_kernel(Side A, Side B, int nbA) {
    using Raw = typename RawT<H>::type;
    Side S; int bucket;
    if ((int)blockIdx.x < nbA) { S = A; bucket = blockIdx.x; }
    else                       { S = B; bucket = blockIdx.x - nbA; }
    __shared__ int fh[FPB], fcur[FPB], foff[FPB], sc[FPB];
    __shared__ unsigned char rmap[FPB];
    __shared__ int fsrc[GCAP];
    int t = threadIdx.x;
    if (t < FPB) fh[t] = 0;
    __syncthreads();
    const int* pbase = S.pairs + (size_t)bucket * GCAP;
    int cnt = min(S.cur[bucket], GCAP);
    for (int i = t; i < cnt; i += 256)
        atomicAdd(&fh[pbase[i] & FMASK], 1);
    __syncthreads();
    if (t < FPB) sc[t] = fh[t];
    __syncthreads();
    for (int off = 1; off < FPB; off <<= 1) {
        int v = 0;
        if (t < FPB) v = sc[t] + ((t >= off) ? sc[t - off] : 0);
        __syncthreads();
        if (t < FPB) sc[t] = v;
        __syncthreads();
    }
    if (t < FPB) { foff[t] = sc[t] - fh[t]; fcur[t] = sc[t] - fh[t]; }
    __syncthreads();
    for (int i = t; i < cnt; i += 256) {
        int v = pbase[i];
        int r = atomicAdd(&fcur[v & FMASK], 1);
        fsrc[r] = v >> SHIFT;
    }
    // rank rows by degree (descending; ties by index)
    if (t < FPB) {
        int c = fh[t];
        int r = 0;
        for (int j = 0; j < FPB; ++j) {
            int cj = fh[j];
            r += (cj > c) || (cj == c && j < t);
        }
        rmap[r] = (unsigned char)t;
    }
    __syncthreads();

    int g = t >> 4, sub = t & 15;
    int base_d = bucket << SHIFT;

    for (int pass = 0; pass < 2; ++pass) {
        int r0 = pass == 0 ? 2 * g     : 62 - 2 * g;
        int r1 = pass == 0 ? 2 * g + 1 : 63 - 2 * g;

#define DECL_CHAIN(J)                                                          \
        int row##J = rmap[r##J];                                               \
        int d##J = base_d + row##J;                                            \
        bool ok##J = d##J < S.n_dst;                                           \
        int s0##J = foff[row##J];                                              \
        int cf##J = ok##J ? fh[row##J] : 0;                                    \
        float4 bv##J = ok##J ? load_dst<H>(S, d##J, sub)                       \
                             : make_float4(0.f, 0.f, 0.f, 0.f);                \
        float ss##J = 0.0f;                                                    \
        float4 acc##J = make_float4(0.f, 0.f, 0.f, 0.f);                       \
        Raw cA##J{}, cB##J{}, cC##J{}, cD##J{}, cE##J{}, cF##J{}, cG##J{}, cH##J{}; \
        if (cf##J > 0) cA##J = raw_load<H>(S, fsrc[s0##J + 0], sub);           \
        if (cf##J > 1) cB##J = raw_load<H>(S, fsrc[s0##J + 1], sub);           \
        if (cf##J > 2) cC##J = raw_load<H>(S, fsrc[s0##J + 2], sub);           \
        if (cf##J > 3) cD##J = raw_load<H>(S, fsrc[s0##J + 3], sub);           \
        if (cf##J > 4) cE##J = raw_load<H>(S, fsrc[s0##J + 4], sub);           \
        if (cf##J > 5) cF##J = raw_load<H>(S, fsrc[s0##J + 5], sub);           \
        if (cf##J > 6) cG##J = raw_load<H>(S, fsrc[s0##J + 6], sub);           \
        if (cf##J > 7) cH##J = raw_load<H>(S, fsrc[s0##J + 7], sub);

        DECL_CHAIN(0) DECL_CHAIN(1)

#define STEP(J, RV, KK)                                                        \
            if ((KK) < cf##J) {                                                \
                float4 AV = to_f4<H>(RV);                                      \
                float p = AV.x * bv##J.x + AV.y * bv##J.y +                    \
                          AV.z * bv##J.z + AV.w * bv##J.w;                     \
                p = row16_allsum(p);                                           \
                p = fmaxf(p, NEG_SLOPE * p);   /* leaky relu, branch-free */   \
                float w = __expf(fminf(p, 85.0f));                             \
                ss##J += w;                                                    \
                acc##J.x += w * AV.x; acc##J.y += w * AV.y;                    \
                acc##J.z += w * AV.z; acc##J.w += w * AV.w;                    \
            }

        int kmax = max(cf0, cf1);
        for (int k = 0; k < kmax; k += 8) {
            // issue next 8 gathers per chain (two-set copy pattern, no rotation)
            Raw nA0{}, nB0{}, nC0{}, nD0{}, nE0{}, nF0{}, nG0{}, nH0{};
            Raw nA1{}, nB1{}, nC1{}, nD1{}, nE1{}, nF1{}, nG1{}, nH1{};
            if (k + 8  < cf0) nA0 = raw_load<H>(S, fsrc[s00 + k + 8],  sub);
            if (k + 9  < cf0) nB0 = raw_load<H>(S, fsrc[s00 + k + 9],  sub);
            if (k + 10 < cf0) nC0 = raw_load<H>(S, fsrc[s00 + k + 10], sub);
            if (k + 11 < cf0) nD0 = raw_load<H>(S, fsrc[s00 + k + 11], sub);
            if (k + 12 < cf0) nE0 = raw_load<H>(S, fsrc[s00 + k + 12], sub);
            if (k + 13 < cf0) nF0 = raw_load<H>(S, fsrc[s00 + k + 13], sub);
            if (k + 14 < cf0) nG0 = raw_load<H>(S, fsrc[s00 + k + 14], sub);
            if (k + 15 < cf0) nH0 = raw_load<H>(S, fsrc[s00 + k + 15], sub);
            if (k + 8  < cf1) nA1 = raw_load<H>(S, fsrc[s01 + k + 8],  sub);
            if (k + 9  < cf1) nB1 = raw_load<H>(S, fsrc[s01 + k + 9],  sub);
            if (k + 10 < cf1) nC1 = raw_load<H>(S, fsrc[s01 + k + 10], sub);
            if (k + 11 < cf1) nD1 = raw_load<H>(S, fsrc[s01 + k + 11], sub);
            if (k + 12 < cf1) nE1 = raw_load<H>(S, fsrc[s01 + k + 12], sub);
            if (k + 13 < cf1) nF1 = raw_load<H>(S, fsrc[s01 + k + 13], sub);
            if (k + 14 < cf1) nG1 = raw_load<H>(S, fsrc[s01 + k + 14], sub);
            if (k + 15 < cf1) nH1 = raw_load<H>(S, fsrc[s01 + k + 15], sub);

            STEP(0, cA0, k)     STEP(1, cA1, k)
            STEP(0, cB0, k + 1) STEP(1, cB1, k + 1)
            STEP(0, cC0, k + 2) STEP(1, cC1, k + 2)
            STEP(0, cD0, k + 3) STEP(1, cD1, k + 3)
            STEP(0, cE0, k + 4) STEP(1, cE1, k + 4)
            STEP(0, cF0, k + 5) STEP(1, cF1, k + 5)
            STEP(0, cG0, k + 6) STEP(1, cG1, k + 6)
            STEP(0, cH0, k + 7) STEP(1, cH1, k + 7)

            cA0 = nA0; cB0 = nB0; cC0 = nC0; cD0 = nD0;
            cE0 = nE0; cF0 = nF0; cG0 = nG0; cH0 = nH0;
            cA1 = nA1; cB1 = nB1; cC1 = nC1; cD1 = nD1;
            cE1 = nE1; cF1 = nF1; cG1 = nG1; cH1 = nH1;
        }

#define STORE_CHAIN(J)                                                         \
        if (ok##J) {                                                           \
            float inv = (ss##J > 0.0f) ? 1.0f / ss##J : 0.0f;                  \
            *reinterpret_cast<float4*>(                                        \
                S.out + (size_t)d##J * EMB_DIM + sub * 4) =                    \
                make_float4(acc##J.x * inv, acc##J.y * inv,                    \
                            acc##J.z * inv, acc##J.w * inv);                   \
        }
        STORE_CHAIN(0) STORE_CHAIN(1)
    }
}

// ---------- host orchestration ----------------------------------------------
extern "C" void kernel_launch(void* const* d_in, const int* in_sizes, int n_in,
                              void* d_out, int out_size, void* d_ws, size_t ws_size,
                              hipStream_t stream) {
    const float* user_emb = (const float*)d_in[0];
    const float* item_emb = (const float*)d_in[1];
    const int* ui_src = (const int*)d_in[2];
    const int* ui_dst = (const int*)d_in[3];
    const int* iu_src = (const int*)d_in[4];
    const int* iu_dst = (const int*)d_in[5];

    float* out = (float*)d_out;
    float* item_out = out;                              // [N_ITEM, 64]
    float* user_out = out + (size_t)N_ITEM * EMB_DIM;   // [N_USER, 64]

    const int E0 = in_sizes[2];
    const int E1 = in_sizes[4];

    Side A, B;
    A.srcf = user_emb; A.dstf = item_emb; A.src = ui_src; A.dst = ui_dst;
    A.E = E0; A.n_dst = N_ITEM; A.out = item_out; A.srch = nullptr; A.dsth = nullptr;
    B.srcf = item_emb; B.dstf = user_emb; B.src = iu_src; B.dst = iu_dst;
    B.E = E1; B.n_dst = N_USER; B.out = user_out; B.srch = nullptr; B.dsth = nullptr;

    const size_t half_elems  = (size_t)(N_USER + N_ITEM) * EMB_DIM;
    const size_t half_bytes  = half_elems * sizeof(__half);          // 25.6 MB
    const size_t pairs_bytes = (size_t)NB * GCAP * 4;                // 6.4 MB/side
    const size_t cur_bytes   = (size_t)NB * 4;
    const size_t need_fixed32 = 2 * (pairs_bytes + cur_bytes);       // ~12.8 MB
    const size_t need_fixed16 = need_fixed32 + half_bytes;           // ~38.4 MB

    const bool use_fp16 = ws_size >= need_fixed16;
    char* wsb = (char*)d_ws;
    __half* hu = nullptr; __half* hi = nullptr;
    if (use_fp16) {
        hu = (__half*)wsb;
        hi = hu + (size_t)N_USER * EMB_DIM;
        wsb += half_bytes;
        A.srch = hu; A.dsth = hi;   // A: gathers user rows, dst = item rows
        B.srch = hi; B.dsth = hu;   // B: gathers item rows, dst = user rows
    }
    A.cur   = (int*)wsb;
    B.cur   = A.cur + NB;
    A.pairs = B.cur + NB;
    B.pairs = A.pairs + (size_t)NB * GCAP;

    // zero cursors only (pairs slots in use are fully overwritten)
    hipMemsetAsync(A.cur, 0, 2 * cur_bytes, stream);

    const int nbinA = (E0 + BIN_TILE - 1) / BIN_TILE;
    const int nbinB = (E1 + BIN_TILE - 1) / BIN_TILE;
    const int cvt_blocks = use_fp16 ? (int)(half_elems / 4 / 512) : 0;  // 6250

    prep_kernel<<<nbinA + nbinB + cvt_blocks, 512, 0, stream>>>(
        A, B, nbinA, nbinB,
        use_fp16 ? user_emb : nullptr, use_fp16 ? item_emb : nullptr, hu, hi);

    if (use_fp16) gat_kernel<true><<<2 * NB, 256, 0, stream>>>(A, B, NB);
    else          gat_kernel<false><<<2 * NB, 256, 0, stream>>>(A, B, NB);
}

// Round 16
// 113.342 us; speedup vs baseline: 2.1502x; 2.1502x over previous
//
#include <hip/hip_runtime.h>
#include <hip/hip_bf16.h>
#include <hip/hip_fp16.h>

#define N_USER 100000
#define N_ITEM 100000
#define EMB_DIM 64
#define NEG_SLOPE 0.2f

#define SHIFT 6              // 64 fine dst per coarse bucket
#define FPB 64               // 1 << SHIFT
#define FMASK 63
#define NB 1563              // ceil(100000 / 64), same for both sides
#define GCAP 1024            // fixed slot capacity per bucket (avg 640, +15 sigma)
#define BIN_TILE 16384       // 16K-edge tiles: halves cur-atomic contention

struct Side {
    const float*  srcf;   // fp32 src table
    const __half* srch;   // fp16 src table (fp16 tier only)
    const float*  dstf;   // fp32 dst table
    const __half* dsth;   // fp16 dst table (fp16 tier only; = other half-table)
    const int*    src;
    const int*    dst;
    int           E;
    int           n_dst;
    int*          cur;    // [NB] atomic cursors (init 0; final value = count)
    int*          pairs;  // [NB*GCAP] packed (src<<SHIFT)|fine, fixed-stride
    float*        out;    // [n_dst, EMB_DIM]
};

// ---- DPP 16-lane all-reduce: x += row_ror<N>(x), N=1,2,4,8 (VALU pipe). ----
template <int CTRL>
__device__ __forceinline__ float dpp_add(float x) {
    int v = __builtin_amdgcn_update_dpp(0, __float_as_int(x), CTRL, 0xf, 0xf, true);
    return x + __int_as_float(v);
}
__device__ __forceinline__ float row16_allsum(float p) {
    p = dpp_add<0x121>(p);
    p = dpp_add<0x122>(p);
    p = dpp_add<0x124>(p);
    p = dpp_add<0x128>(p);
    return p;
}

// Raw (unconverted) gather payload: uint2 for fp16 rows, float4 for fp32.
template <bool H> struct RawT;
template <> struct RawT<true>  { using type = uint2;  };
template <> struct RawT<false> { using type = float4; };

template <bool H>
__device__ __forceinline__ typename RawT<H>::type
raw_load(const Side& S, int si, int sub) {
    if constexpr (H) {
        return *reinterpret_cast<const uint2*>(S.srch + (size_t)si * EMB_DIM + sub * 4);
    } else {
        return *reinterpret_cast<const float4*>(S.srcf + (size_t)si * EMB_DIM + sub * 4);
    }
}
template <bool H>
__device__ __forceinline__ float4 to_f4(typename RawT<H>::type v) {
    if constexpr (H) {
        __half2 h0 = *reinterpret_cast<const __half2*>(&v.x);
        __half2 h1 = *reinterpret_cast<const __half2*>(&v.y);
        float2 f0 = __half22float2(h0), f1 = __half22float2(h1);
        return make_float4(f0.x, f0.y, f1.x, f1.y);
    } else {
        return v;
    }
}
template <bool H>
__device__ __forceinline__ float4 load_dst(const Side& S, int d, int sub) {
    if constexpr (H) {
        uint2 v = *reinterpret_cast<const uint2*>(S.dsth + (size_t)d * EMB_DIM + sub * 4);
        return to_f4<true>(v);
    } else {
        return *reinterpret_cast<const float4*>(S.dstf + (size_t)d * EMB_DIM + sub * 4);
    }
}

// ---------- 1. fused prep: fixed-stride bin tiles ∥ fp16 convert ------------
__global__ void prep_kernel(Side A, Side B, int nbinA, int nbinB,
                            const float* tu, const float* ti,
                            __half* hu, __half* hi) {
    int b = blockIdx.x;
    if (b < nbinA + nbinB) {
        __shared__ int h[NB];   // per-tile histogram, then local cursor
        __shared__ int bl[NB];  // per-tile base reservation
        Side S; int lb;
        if (b < nbinA) { S = A; lb = b; }
        else           { S = B; lb = b - nbinA; }
        int t = threadIdx.x;
        for (int i = t; i < NB; i += blockDim.x) h[i] = 0;
        __syncthreads();
        int beg = lb * BIN_TILE;
        int end = min(beg + BIN_TILE, S.E);
        for (int i = beg + t; i < end; i += blockDim.x)
            atomicAdd(&h[S.dst[i] >> SHIFT], 1);
        __syncthreads();
        for (int i = t; i < NB; i += blockDim.x) {
            int c = h[i];
            bl[i] = c ? atomicAdd(&S.cur[i], c) : 0;
            h[i] = 0;  // reuse as local cursor
        }
        __syncthreads();
        for (int i = beg + t; i < end; i += blockDim.x) {
            int d = S.dst[i];
            int bk = d >> SHIFT;
            int r = bl[bk] + atomicAdd(&h[bk], 1);
            if (r < GCAP)  // overflow guard (never hit for random input)
                S.pairs[(size_t)bk * GCAP + r] = (S.src[i] << SHIFT) | (d & FMASK);
        }
    } else if (tu != nullptr) {
        const long n4 = (long)N_USER * EMB_DIM / 4;   // float4s per table
        long i = (long)(b - nbinA - nbinB) * blockDim.x + threadIdx.x;
        const float4* s; uint2* d; long j;
        if (i < n4) { s = (const float4*)tu; d = (uint2*)hu; j = i; }
        else        { s = (const float4*)ti; d = (uint2*)hi; j = i - n4; }
        if (j < n4) {
            float4 v = s[j];
            __half2 p0 = __floats2half2_rn(v.x, v.y);
            __half2 p1 = __floats2half2_rn(v.z, v.w);
            uint2 o;
            o.x = *reinterpret_cast<unsigned int*>(&p0);
            o.y = *reinterpret_cast<unsigned int*>(&p1);
            d[j] = o;
        }
    }
}

// ---------- 2. per-bucket fine sort (LDS) + balanced dual-chain softmax -----
// One block per coarse bucket; 2 chains x 2 passes, degree-rank snake balance.
// Distance-4 two-set ring — MEASURED MAXIMUM: R13's 3-set rotation and R15's
// distance-8 both spill to scratch (WRITE 50->132/263 MB, gat 58->100/190 us).
// Do not deepen. dst rows from fp16 half-tables (cvt output).
// __launch_bounds__(256, 6): A/B-measured — 8 blocks/CU thrashes per-XCD L2
// (FETCH 130->164 MB, gat 59->97 us).
template <bool H>
__global__ void __launch_bounds__(256, 6) gat_kernel(Side A, Side B, int nbA) {
    using Raw = typename RawT<H>::type;
    Side S; int bucket;
    if ((int)blockIdx.x < nbA) { S = A; bucket = blockIdx.x; }
    else                       { S = B; bucket = blockIdx.x - nbA; }
    __shared__ int fh[FPB], fcur[FPB], foff[FPB], sc[FPB];
    __shared__ unsigned char rmap[FPB];
    __shared__ int fsrc[GCAP];
    int t = threadIdx.x;
    if (t < FPB) fh[t] = 0;
    __syncthreads();
    const int* pbase = S.pairs + (size_t)bucket * GCAP;
    int cnt = min(S.cur[bucket], GCAP);
    for (int i = t; i < cnt; i += 256)
        atomicAdd(&fh[pbase[i] & FMASK], 1);
    __syncthreads();
    if (t < FPB) sc[t] = fh[t];
    __syncthreads();
    for (int off = 1; off < FPB; off <<= 1) {
        int v = 0;
        if (t < FPB) v = sc[t] + ((t >= off) ? sc[t - off] : 0);
        __syncthreads();
        if (t < FPB) sc[t] = v;
        __syncthreads();
    }
    if (t < FPB) { foff[t] = sc[t] - fh[t]; fcur[t] = sc[t] - fh[t]; }
    __syncthreads();
    for (int i = t; i < cnt; i += 256) {
        int v = pbase[i];
        int r = atomicAdd(&fcur[v & FMASK], 1);
        fsrc[r] = v >> SHIFT;
    }
    // rank rows by degree (descending; ties by index)
    if (t < FPB) {
        int c = fh[t];
        int r = 0;
        for (int j = 0; j < FPB; ++j) {
            int cj = fh[j];
            r += (cj > c) || (cj == c && j < t);
        }
        rmap[r] = (unsigned char)t;
    }
    __syncthreads();

    int g = t >> 4, sub = t & 15;
    int base_d = bucket << SHIFT;

    for (int pass = 0; pass < 2; ++pass) {
        int r0 = pass == 0 ? 2 * g     : 62 - 2 * g;
        int r1 = pass == 0 ? 2 * g + 1 : 63 - 2 * g;

#define DECL_CHAIN(J)                                                          \
        int row##J = rmap[r##J];                                               \
        int d##J = base_d + row##J;                                            \
        bool ok##J = d##J < S.n_dst;                                           \
        int s0##J = foff[row##J];                                              \
        int cf##J = ok##J ? fh[row##J] : 0;                                    \
        float4 bv##J = ok##J ? load_dst<H>(S, d##J, sub)                       \
                             : make_float4(0.f, 0.f, 0.f, 0.f);                \
        float ss##J = 0.0f;                                                    \
        float4 acc##J = make_float4(0.f, 0.f, 0.f, 0.f);                       \
        Raw rA##J{}, rB##J{}, rC##J{}, rD##J{};                                \
        if (cf##J > 0) rA##J = raw_load<H>(S, fsrc[s0##J + 0], sub);           \
        if (cf##J > 1) rB##J = raw_load<H>(S, fsrc[s0##J + 1], sub);           \
        if (cf##J > 2) rC##J = raw_load<H>(S, fsrc[s0##J + 2], sub);           \
        if (cf##J > 3) rD##J = raw_load<H>(S, fsrc[s0##J + 3], sub);

        DECL_CHAIN(0) DECL_CHAIN(1)

#define STEP(J, RV, KK)                                                        \
            if ((KK) < cf##J) {                                                \
                float4 AV = to_f4<H>(RV);                                      \
                float p = AV.x * bv##J.x + AV.y * bv##J.y +                    \
                          AV.z * bv##J.z + AV.w * bv##J.w;                     \
                p = row16_allsum(p);                                           \
                p = fmaxf(p, NEG_SLOPE * p);   /* leaky relu, branch-free */   \
                float w = __expf(fminf(p, 85.0f));                             \
                ss##J += w;                                                    \
                acc##J.x += w * AV.x; acc##J.y += w * AV.y;                    \
                acc##J.z += w * AV.z; acc##J.w += w * AV.w;                    \
            }

        int kmax = max(cf0, cf1);
        for (int k = 0; k < kmax; k += 4) {
            // issue next 4 gathers per chain (raw, no cvt) before consuming
            Raw nA0{}, nB0{}, nC0{}, nD0{}, nA1{}, nB1{}, nC1{}, nD1{};
            if (k + 4 < cf0) nA0 = raw_load<H>(S, fsrc[s00 + k + 4], sub);
            if (k + 5 < cf0) nB0 = raw_load<H>(S, fsrc[s00 + k + 5], sub);
            if (k + 6 < cf0) nC0 = raw_load<H>(S, fsrc[s00 + k + 6], sub);
            if (k + 7 < cf0) nD0 = raw_load<H>(S, fsrc[s00 + k + 7], sub);
            if (k + 4 < cf1) nA1 = raw_load<H>(S, fsrc[s01 + k + 4], sub);
            if (k + 5 < cf1) nB1 = raw_load<H>(S, fsrc[s01 + k + 5], sub);
            if (k + 6 < cf1) nC1 = raw_load<H>(S, fsrc[s01 + k + 6], sub);
            if (k + 7 < cf1) nD1 = raw_load<H>(S, fsrc[s01 + k + 7], sub);

            STEP(0, rA0, k)     STEP(1, rA1, k)
            STEP(0, rB0, k + 1) STEP(1, rB1, k + 1)
            STEP(0, rC0, k + 2) STEP(1, rC1, k + 2)
            STEP(0, rD0, k + 3) STEP(1, rD1, k + 3)

            rA0 = nA0; rB0 = nB0; rC0 = nC0; rD0 = nD0;
            rA1 = nA1; rB1 = nB1; rC1 = nC1; rD1 = nD1;
        }

#define STORE_CHAIN(J)                                                         \
        if (ok##J) {                                                           \
            float inv = (ss##J > 0.0f) ? 1.0f / ss##J : 0.0f;                  \
            *reinterpret_cast<float4*>(                                        \
                S.out + (size_t)d##J * EMB_DIM + sub * 4) =                    \
                make_float4(acc##J.x * inv, acc##J.y * inv,                    \
                            acc##J.z * inv, acc##J.w * inv);                   \
        }
        STORE_CHAIN(0) STORE_CHAIN(1)
    }
}

// ---------- host orchestration ----------------------------------------------
extern "C" void kernel_launch(void* const* d_in, const int* in_sizes, int n_in,
                              void* d_out, int out_size, void* d_ws, size_t ws_size,
                              hipStream_t stream) {
    const float* user_emb = (const float*)d_in[0];
    const float* item_emb = (const float*)d_in[1];
    const int* ui_src = (const int*)d_in[2];
    const int* ui_dst = (const int*)d_in[3];
    const int* iu_src = (const int*)d_in[4];
    const int* iu_dst = (const int*)d_in[5];

    float* out = (float*)d_out;
    float* item_out = out;                              // [N_ITEM, 64]
    float* user_out = out + (size_t)N_ITEM * EMB_DIM;   // [N_USER, 64]

    const int E0 = in_sizes[2];
    const int E1 = in_sizes[4];

    Side A, B;
    A.srcf = user_emb; A.dstf = item_emb; A.src = ui_src; A.dst = ui_dst;
    A.E = E0; A.n_dst = N_ITEM; A.out = item_out; A.srch = nullptr; A.dsth = nullptr;
    B.srcf = item_emb; B.dstf = user_emb; B.src = iu_src; B.dst = iu_dst;
    B.E = E1; B.n_dst = N_USER; B.out = user_out; B.srch = nullptr; B.dsth = nullptr;

    const size_t half_elems  = (size_t)(N_USER + N_ITEM) * EMB_DIM;
    const size_t half_bytes  = half_elems * sizeof(__half);          // 25.6 MB
    const size_t pairs_bytes = (size_t)NB * GCAP * 4;                // 6.4 MB/side
    const size_t cur_bytes   = (size_t)NB * 4;
    const size_t need_fixed32 = 2 * (pairs_bytes + cur_bytes);       // ~12.8 MB
    const size_t need_fixed16 = need_fixed32 + half_bytes;           // ~38.4 MB

    const bool use_fp16 = ws_size >= need_fixed16;
    char* wsb = (char*)d_ws;
    __half* hu = nullptr; __half* hi = nullptr;
    if (use_fp16) {
        hu = (__half*)wsb;
        hi = hu + (size_t)N_USER * EMB_DIM;
        wsb += half_bytes;
        A.srch = hu; A.dsth = hi;   // A: gathers user rows, dst = item rows
        B.srch = hi; B.dsth = hu;   // B: gathers item rows, dst = user rows
    }
    A.cur   = (int*)wsb;
    B.cur   = A.cur + NB;
    A.pairs = B.cur + NB;
    B.pairs = A.pairs + (size_t)NB * GCAP;

    // zero cursors only (pairs slots in use are fully overwritten)
    hipMemsetAsync(A.cur, 0, 2 * cur_bytes, stream);

    const int nbinA = (E0 + BIN_TILE - 1) / BIN_TILE;
    const int nbinB = (E1 + BIN_TILE - 1) / BIN_TILE;
    const int cvt_blocks = use_fp16 ? (int)(half_elems / 4 / 512) : 0;  // 6250

    prep_kernel<<<nbinA + nbinB + cvt_blocks, 512, 0, stream>>>(
        A, B, nbinA, nbinB,
        use_fp16 ? user_emb : nullptr, use_fp16 ? item_emb : nullptr, hu, hi);

    if (use_fp16) gat_kernel<true><<<2 * NB, 256, 0, stream>>>(A, B, NB);
    else          gat_kernel<false><<<2 * NB, 256, 0, stream>>>(A, B, NB);
}

// Round 17
// 99.893 us; speedup vs baseline: 2.4397x; 1.1346x over previous
//
#include <hip/hip_runtime.h>
#include <hip/hip_bf16.h>
#include <hip/hip_fp16.h>

#define N_USER 100000
#define N_ITEM 100000
#define EMB_DIM 64
#define NEG_SLOPE 0.2f

#define SHIFT 6              // 64 fine dst per coarse bucket
#define FPB 64               // 1 << SHIFT
#define FMASK 63
#define NB 1563              // ceil(100000 / 64), same for both sides
#define GCAP 1024            // fixed slot capacity per bucket (avg 640, +15 sigma)
#define BIN_TILE 8192        // A/B-measured: 16384 halves bin-block count below
                             // machine width -> prep 37->70 us (R16). Keep 8192.

struct Side {
    const float*  srcf;   // fp32 src table
    const __half* srch;   // fp16 src table (fp16 tier only)
    const float*  dstf;   // fp32 dst table
    const __half* dsth;   // fp16 dst table (fp16 tier only; = other half-table)
    const int*    src;
    const int*    dst;
    int           E;
    int           n_dst;
    int*          cur;    // [NB] atomic cursors (init 0; final value = count)
    int*          pairs;  // [NB*GCAP] packed (src<<SHIFT)|fine, fixed-stride
    float*        out;    // [n_dst, EMB_DIM]
};

// ---- DPP 16-lane all-reduce: x += row_ror<N>(x), N=1,2,4,8 (VALU pipe). ----
template <int CTRL>
__device__ __forceinline__ float dpp_add(float x) {
    int v = __builtin_amdgcn_update_dpp(0, __float_as_int(x), CTRL, 0xf, 0xf, true);
    return x + __int_as_float(v);
}
__device__ __forceinline__ float row16_allsum(float p) {
    p = dpp_add<0x121>(p);
    p = dpp_add<0x122>(p);
    p = dpp_add<0x124>(p);
    p = dpp_add<0x128>(p);
    return p;
}

// Raw (unconverted) gather payload: uint2 for fp16 rows, float4 for fp32.
template <bool H> struct RawT;
template <> struct RawT<true>  { using type = uint2;  };
template <> struct RawT<false> { using type = float4; };

template <bool H>
__device__ __forceinline__ typename RawT<H>::type
raw_load(const Side& S, int si, int sub) {
    if constexpr (H) {
        return *reinterpret_cast<const uint2*>(S.srch + (size_t)si * EMB_DIM + sub * 4);
    } else {
        return *reinterpret_cast<const float4*>(S.srcf + (size_t)si * EMB_DIM + sub * 4);
    }
}
template <bool H>
__device__ __forceinline__ float4 to_f4(typename RawT<H>::type v) {
    if constexpr (H) {
        __half2 h0 = *reinterpret_cast<const __half2*>(&v.x);
        __half2 h1 = *reinterpret_cast<const __half2*>(&v.y);
        float2 f0 = __half22float2(h0), f1 = __half22float2(h1);
        return make_float4(f0.x, f0.y, f1.x, f1.y);
    } else {
        return v;
    }
}
template <bool H>
__device__ __forceinline__ float4 load_dst(const Side& S, int d, int sub) {
    if constexpr (H) {
        uint2 v = *reinterpret_cast<const uint2*>(S.dsth + (size_t)d * EMB_DIM + sub * 4);
        return to_f4<true>(v);
    } else {
        return *reinterpret_cast<const float4*>(S.dstf + (size_t)d * EMB_DIM + sub * 4);
    }
}

// ---------- 1. fused prep: fixed-stride bin tiles ∥ fp16 convert ------------
__global__ void prep_kernel(Side A, Side B, int nbinA, int nbinB,
                            const float* tu, const float* ti,
                            __half* hu, __half* hi) {
    int b = blockIdx.x;
    if (b < nbinA + nbinB) {
        __shared__ int h[NB];   // per-tile histogram, then local cursor
        __shared__ int bl[NB];  // per-tile base reservation
        Side S; int lb;
        if (b < nbinA) { S = A; lb = b; }
        else           { S = B; lb = b - nbinA; }
        int t = threadIdx.x;
        for (int i = t; i < NB; i += blockDim.x) h[i] = 0;
        __syncthreads();
        int beg = lb * BIN_TILE;
        int end = min(beg + BIN_TILE, S.E);
        for (int i = beg + t; i < end; i += blockDim.x)
            atomicAdd(&h[S.dst[i] >> SHIFT], 1);
        __syncthreads();
        for (int i = t; i < NB; i += blockDim.x) {
            int c = h[i];
            bl[i] = c ? atomicAdd(&S.cur[i], c) : 0;
            h[i] = 0;  // reuse as local cursor
        }
        __syncthreads();
        for (int i = beg + t; i < end; i += blockDim.x) {
            int d = S.dst[i];
            int bk = d >> SHIFT;
            int r = bl[bk] + atomicAdd(&h[bk], 1);
            if (r < GCAP)  // overflow guard (never hit for random input)
                S.pairs[(size_t)bk * GCAP + r] = (S.src[i] << SHIFT) | (d & FMASK);
        }
    } else if (tu != nullptr) {
        const long n4 = (long)N_USER * EMB_DIM / 4;   // float4s per table
        long i = (long)(b - nbinA - nbinB) * blockDim.x + threadIdx.x;
        const float4* s; uint2* d; long j;
        if (i < n4) { s = (const float4*)tu; d = (uint2*)hu; j = i; }
        else        { s = (const float4*)ti; d = (uint2*)hi; j = i - n4; }
        if (j < n4) {
            float4 v = s[j];
            __half2 p0 = __floats2half2_rn(v.x, v.y);
            __half2 p1 = __floats2half2_rn(v.z, v.w);
            uint2 o;
            o.x = *reinterpret_cast<unsigned int*>(&p0);
            o.y = *reinterpret_cast<unsigned int*>(&p1);
            d[j] = o;
        }
    }
}

// ---------- 2. per-bucket fine sort (LDS) + balanced dual-chain softmax -----
// One block per coarse bucket; 2 chains x 2 passes, degree-rank snake balance.
// Distance-4 two-set ring — MEASURED MAXIMUM: R13's 3-set rotation and R15's
// distance-8 both spill to scratch (WRITE 50->132/263 MB, gat 58->100/190 us).
// Do not deepen. dst rows from fp16 half-tables (cvt output).
// __launch_bounds__(256, 6): A/B-measured — 8 blocks/CU thrashes per-XCD L2
// (FETCH 130->164 MB, gat 59->97 us).
template <bool H>
__global__ void __launch_bounds__(256, 6) gat_kernel(Side A, Side B, int nbA) {
    using Raw = typename RawT<H>::type;
    Side S; int bucket;
    if ((int)blockIdx.x < nbA) { S = A; bucket = blockIdx.x; }
    else                       { S = B; bucket = blockIdx.x - nbA; }
    __shared__ int fh[FPB], fcur[FPB], foff[FPB], sc[FPB];
    __shared__ unsigned char rmap[FPB];
    __shared__ int fsrc[GCAP];
    int t = threadIdx.x;
    if (t < FPB) fh[t] = 0;
    __syncthreads();
    const int* pbase = S.pairs + (size_t)bucket * GCAP;
    int cnt = min(S.cur[bucket], GCAP);
    for (int i = t; i < cnt; i += 256)
        atomicAdd(&fh[pbase[i] & FMASK], 1);
    __syncthreads();
    if (t < FPB) sc[t] = fh[t];
    __syncthreads();
    for (int off = 1; off < FPB; off <<= 1) {
        int v = 0;
        if (t < FPB) v = sc[t] + ((t >= off) ? sc[t - off] : 0);
        __syncthreads();
        if (t < FPB) sc[t] = v;
        __syncthreads();
    }
    if (t < FPB) { foff[t] = sc[t] - fh[t]; fcur[t] = sc[t] - fh[t]; }
    __syncthreads();
    for (int i = t; i < cnt; i += 256) {
        int v = pbase[i];
        int r = atomicAdd(&fcur[v & FMASK], 1);
        fsrc[r] = v >> SHIFT;
    }
    // rank rows by degree (descending; ties by index)
    if (t < FPB) {
        int c = fh[t];
        int r = 0;
        for (int j = 0; j < FPB; ++j) {
            int cj = fh[j];
            r += (cj > c) || (cj == c && j < t);
        }
        rmap[r] = (unsigned char)t;
    }
    __syncthreads();

    int g = t >> 4, sub = t & 15;
    int base_d = bucket << SHIFT;

    for (int pass = 0; pass < 2; ++pass) {
        int r0 = pass == 0 ? 2 * g     : 62 - 2 * g;
        int r1 = pass == 0 ? 2 * g + 1 : 63 - 2 * g;

#define DECL_CHAIN(J)                                                          \
        int row##J = rmap[r##J];                                               \
        int d##J = base_d + row##J;                                            \
        bool ok##J = d##J < S.n_dst;                                           \
        int s0##J = foff[row##J];                                              \
        int cf##J = ok##J ? fh[row##J] : 0;                                    \
        float4 bv##J = ok##J ? load_dst<H>(S, d##J, sub)                       \
                             : make_float4(0.f, 0.f, 0.f, 0.f);                \
        float ss##J = 0.0f;                                                    \
        float4 acc##J = make_float4(0.f, 0.f, 0.f, 0.f);                       \
        Raw rA##J{}, rB##J{}, rC##J{}, rD##J{};                                \
        if (cf##J > 0) rA##J = raw_load<H>(S, fsrc[s0##J + 0], sub);           \
        if (cf##J > 1) rB##J = raw_load<H>(S, fsrc[s0##J + 1], sub);           \
        if (cf##J > 2) rC##J = raw_load<H>(S, fsrc[s0##J + 2], sub);           \
        if (cf##J > 3) rD##J = raw_load<H>(S, fsrc[s0##J + 3], sub);

        DECL_CHAIN(0) DECL_CHAIN(1)

#define STEP(J, RV, KK)                                                        \
            if ((KK) < cf##J) {                                                \
                float4 AV = to_f4<H>(RV);                                      \
                float p = AV.x * bv##J.x + AV.y * bv##J.y +                    \
                          AV.z * bv##J.z + AV.w * bv##J.w;                     \
                p = row16_allsum(p);                                           \
                p = fmaxf(p, NEG_SLOPE * p);   /* leaky relu, branch-free */   \
                float w = __expf(fminf(p, 85.0f));                             \
                ss##J += w;                                                    \
                acc##J.x += w * AV.x; acc##J.y += w * AV.y;                    \
                acc##J.z += w * AV.z; acc##J.w += w * AV.w;                    \
            }

        int kmax = max(cf0, cf1);
        for (int k = 0; k < kmax; k += 4) {
            // issue next 4 gathers per chain (raw, no cvt) before consuming
            Raw nA0{}, nB0{}, nC0{}, nD0{}, nA1{}, nB1{}, nC1{}, nD1{};
            if (k + 4 < cf0) nA0 = raw_load<H>(S, fsrc[s00 + k + 4], sub);
            if (k + 5 < cf0) nB0 = raw_load<H>(S, fsrc[s00 + k + 5], sub);
            if (k + 6 < cf0) nC0 = raw_load<H>(S, fsrc[s00 + k + 6], sub);
            if (k + 7 < cf0) nD0 = raw_load<H>(S, fsrc[s00 + k + 7], sub);
            if (k + 4 < cf1) nA1 = raw_load<H>(S, fsrc[s01 + k + 4], sub);
            if (k + 5 < cf1) nB1 = raw_load<H>(S, fsrc[s01 + k + 5], sub);
            if (k + 6 < cf1) nC1 = raw_load<H>(S, fsrc[s01 + k + 6], sub);
            if (k + 7 < cf1) nD1 = raw_load<H>(S, fsrc[s01 + k + 7], sub);

            STEP(0, rA0, k)     STEP(1, rA1, k)
            STEP(0, rB0, k + 1) STEP(1, rB1, k + 1)
            STEP(0, rC0, k + 2) STEP(1, rC1, k + 2)
            STEP(0, rD0, k + 3) STEP(1, rD1, k + 3)

            rA0 = nA0; rB0 = nB0; rC0 = nC0; rD0 = nD0;
            rA1 = nA1; rB1 = nB1; rC1 = nC1; rD1 = nD1;
        }

#define STORE_CHAIN(J)                                                         \
        if (ok##J) {                                                           \
            float inv = (ss##J > 0.0f) ? 1.0f / ss##J : 0.0f;                  \
            *reinterpret_cast<float4*>(                                        \
                S.out + (size_t)d##J * EMB_DIM + sub * 4) =                    \
                make_float4(acc##J.x * inv, acc##J.y * inv,                    \
                            acc##J.z * inv, acc##J.w * inv);                   \
        }
        STORE_CHAIN(0) STORE_CHAIN(1)
    }
}

// ---------- host orchestration ----------------------------------------------
extern "C" void kernel_launch(void* const* d_in, const int* in_sizes, int n_in,
                              void* d_out, int out_size, void* d_ws, size_t ws_size,
                              hipStream_t stream) {
    const float* user_emb = (const float*)d_in[0];
    const float* item_emb = (const float*)d_in[1];
    const int* ui_src = (const int*)d_in[2];
    const int* ui_dst = (const int*)d_in[3];
    const int* iu_src = (const int*)d_in[4];
    const int* iu_dst = (const int*)d_in[5];

    float* out = (float*)d_out;
    float* item_out = out;                              // [N_ITEM, 64]
    float* user_out = out + (size_t)N_ITEM * EMB_DIM;   // [N_USER, 64]

    const int E0 = in_sizes[2];
    const int E1 = in_sizes[4];

    Side A, B;
    A.srcf = user_emb; A.dstf = item_emb; A.src = ui_src; A.dst = ui_dst;
    A.E = E0; A.n_dst = N_ITEM; A.out = item_out; A.srch = nullptr; A.dsth = nullptr;
    B.srcf = item_emb; B.dstf = user_emb; B.src = iu_src; B.dst = iu_dst;
    B.E = E1; B.n_dst = N_USER; B.out = user_out; B.srch = nullptr; B.dsth = nullptr;

    const size_t half_elems  = (size_t)(N_USER + N_ITEM) * EMB_DIM;
    const size_t half_bytes  = half_elems * sizeof(__half);          // 25.6 MB
    const size_t pairs_bytes = (size_t)NB * GCAP * 4;                // 6.4 MB/side
    const size_t cur_bytes   = (size_t)NB * 4;
    const size_t need_fixed32 = 2 * (pairs_bytes + cur_bytes);       // ~12.8 MB
    const size_t need_fixed16 = need_fixed32 + half_bytes;           // ~38.4 MB

    const bool use_fp16 = ws_size >= need_fixed16;
    char* wsb = (char*)d_ws;
    __half* hu = nullptr; __half* hi = nullptr;
    if (use_fp16) {
        hu = (__half*)wsb;
        hi = hu + (size_t)N_USER * EMB_DIM;
        wsb += half_bytes;
        A.srch = hu; A.dsth = hi;   // A: gathers user rows, dst = item rows
        B.srch = hi; B.dsth = hu;   // B: gathers item rows, dst = user rows
    }
    A.cur   = (int*)wsb;
    B.cur   = A.cur + NB;
    A.pairs = B.cur + NB;
    B.pairs = A.pairs + (size_t)NB * GCAP;

    // zero cursors only (pairs slots in use are fully overwritten)
    hipMemsetAsync(A.cur, 0, 2 * cur_bytes, stream);

    const int nbinA = (E0 + BIN_TILE - 1) / BIN_TILE;
    const int nbinB = (E1 + BIN_TILE - 1) / BIN_TILE;
    const int cvt_blocks = use_fp16 ? (int)(half_elems / 4 / 512) : 0;  // 6250

    prep_kernel<<<nbinA + nbinB + cvt_blocks, 512, 0, stream>>>(
        A, B, nbinA, nbinB,
        use_fp16 ? user_emb : nullptr, use_fp16 ? item_emb : nullptr, hu, hi);

    if (use_fp16) gat_kernel<true><<<2 * NB, 256, 0, stream>>>(A, B, NB);
    else          gat_kernel<false><<<2 * NB, 256, 0, stream>>>(A, B, NB);
}

// Round 18
// 98.631 us; speedup vs baseline: 2.4709x; 1.0128x over previous
//
#include <hip/hip_runtime.h>
#include <hip/hip_bf16.h>
#include <hip/hip_fp16.h>

#define N_USER 100000
#define N_ITEM 100000
#define EMB_DIM 64
#define NEG_SLOPE 0.2f

#define SHIFT 6              // 64 fine dst per coarse bucket
#define FPB 64               // 1 << SHIFT
#define FMASK 63
#define NB 1563              // ceil(100000 / 64), same for both sides
#define GCAP 1024            // fixed slot capacity per bucket (avg 640, +15 sigma)
#define BIN_TILE 8192        // A/B-measured: 16384 halves bin-block count below
                             // machine width -> prep 37->70 us (R16). Keep 8192.

struct Side {
    const float*  srcf;   // fp32 src table
    const __half* srch;   // fp16 src table (fp16 tier only)
    const float*  dstf;   // fp32 dst table
    const __half* dsth;   // fp16 dst table (fp16 tier only; = other half-table)
    const int*    src;
    const int*    dst;
    int           E;
    int           n_dst;
    int*          cur;    // [NB] atomic cursors (init 0; final value = count)
    int*          pairs;  // [NB*GCAP] packed (src<<SHIFT)|fine, fixed-stride
    float*        out;    // [n_dst, EMB_DIM]
};

// ---- DPP 16-lane all-reduce: x += row_ror<N>(x), N=1,2,4,8 (VALU pipe). ----
template <int CTRL>
__device__ __forceinline__ float dpp_add(float x) {
    int v = __builtin_amdgcn_update_dpp(0, __float_as_int(x), CTRL, 0xf, 0xf, true);
    return x + __int_as_float(v);
}
__device__ __forceinline__ float row16_allsum(float p) {
    p = dpp_add<0x121>(p);
    p = dpp_add<0x122>(p);
    p = dpp_add<0x124>(p);
    p = dpp_add<0x128>(p);
    return p;
}

// Raw (unconverted) gather payload: uint2 for fp16 rows, float4 for fp32.
template <bool H> struct RawT;
template <> struct RawT<true>  { using type = uint2;  };
template <> struct RawT<false> { using type = float4; };

template <bool H>
__device__ __forceinline__ typename RawT<H>::type
raw_load(const Side& S, int si, int sub) {
    if constexpr (H) {
        return *reinterpret_cast<const uint2*>(S.srch + (size_t)si * EMB_DIM + sub * 4);
    } else {
        return *reinterpret_cast<const float4*>(S.srcf + (size_t)si * EMB_DIM + sub * 4);
    }
}
template <bool H>
__device__ __forceinline__ float4 to_f4(typename RawT<H>::type v) {
    if constexpr (H) {
        __half2 h0 = *reinterpret_cast<const __half2*>(&v.x);
        __half2 h1 = *reinterpret_cast<const __half2*>(&v.y);
        float2 f0 = __half22float2(h0), f1 = __half22float2(h1);
        return make_float4(f0.x, f0.y, f1.x, f1.y);
    } else {
        return v;
    }
}
template <bool H>
__device__ __forceinline__ float4 load_dst(const Side& S, int d, int sub) {
    if constexpr (H) {
        uint2 v = *reinterpret_cast<const uint2*>(S.dsth + (size_t)d * EMB_DIM + sub * 4);
        return to_f4<true>(v);
    } else {
        return *reinterpret_cast<const float4*>(S.dstf + (size_t)d * EMB_DIM + sub * 4);
    }
}

// ---------- 1. fused prep: fixed-stride bin tiles ∥ fp16 convert ------------
__global__ void prep_kernel(Side A, Side B, int nbinA, int nbinB,
                            const float* tu, const float* ti,
                            __half* hu, __half* hi) {
    int b = blockIdx.x;
    if (b < nbinA + nbinB) {
        __shared__ int h[NB];   // per-tile histogram, then local cursor
        __shared__ int bl[NB];  // per-tile base reservation
        Side S; int lb;
        if (b < nbinA) { S = A; lb = b; }
        else           { S = B; lb = b - nbinA; }
        int t = threadIdx.x;
        for (int i = t; i < NB; i += blockDim.x) h[i] = 0;
        __syncthreads();
        int beg = lb * BIN_TILE;
        int end = min(beg + BIN_TILE, S.E);
        for (int i = beg + t; i < end; i += blockDim.x)
            atomicAdd(&h[S.dst[i] >> SHIFT], 1);
        __syncthreads();
        for (int i = t; i < NB; i += blockDim.x) {
            int c = h[i];
            bl[i] = c ? atomicAdd(&S.cur[i], c) : 0;
            h[i] = 0;  // reuse as local cursor
        }
        __syncthreads();
        for (int i = beg + t; i < end; i += blockDim.x) {
            int d = S.dst[i];
            int bk = d >> SHIFT;
            int r = bl[bk] + atomicAdd(&h[bk], 1);
            if (r < GCAP)  // overflow guard (never hit for random input)
                S.pairs[(size_t)bk * GCAP + r] = (S.src[i] << SHIFT) | (d & FMASK);
        }
    } else if (tu != nullptr) {
        const long n4 = (long)N_USER * EMB_DIM / 4;   // float4s per table
        long i = (long)(b - nbinA - nbinB) * blockDim.x + threadIdx.x;
        const float4* s; uint2* d; long j;
        if (i < n4) { s = (const float4*)tu; d = (uint2*)hu; j = i; }
        else        { s = (const float4*)ti; d = (uint2*)hi; j = i - n4; }
        if (j < n4) {
            float4 v = s[j];
            __half2 p0 = __floats2half2_rn(v.x, v.y);
            __half2 p1 = __floats2half2_rn(v.z, v.w);
            uint2 o;
            o.x = *reinterpret_cast<unsigned int*>(&p0);
            o.y = *reinterpret_cast<unsigned int*>(&p1);
            d[j] = o;
        }
    }
}

// ---------- 2. per-bucket fine sort (LDS) + balanced dual-chain softmax -----
// One block per coarse bucket; 2 chains x 2 passes, degree-rank snake balance.
// XCD-PARTITIONED bucket assignment: dispatch round-robins blockIdx across the
// 8 XCDs, so XCDs 0-3 take side-A buckets and XCDs 4-7 side-B. Each XCD's 4MB
// L2 then serves ONE 12.8MB fp16 gather table instead of a 25.6MB mixture.
// Mapping is a perf heuristic only — any dispatch order stays correct.
// Distance-4 two-set ring — MEASURED MAXIMUM (R13/R15 spill). bounds(256,6) —
// MEASURED (R9/R10 thrash at 8 blocks/CU).
template <bool H>
__global__ void __launch_bounds__(256, 6) gat_kernel(Side A, Side B, int nbA) {
    using Raw = typename RawT<H>::type;
    int i = blockIdx.x;
    int xcd = i & 7;
    int sideSel = xcd >> 2;                  // XCD 0-3 -> A, 4-7 -> B
    int bucket = (i >> 3) * 4 + (xcd & 3);   // within-side ordinal
    if (bucket >= nbA) return;               // (nbA == NB for both sides)
    Side S = sideSel ? B : A;
    __shared__ int fh[FPB], fcur[FPB], foff[FPB], sc[FPB];
    __shared__ unsigned char rmap[FPB];
    __shared__ int fsrc[GCAP];
    int t = threadIdx.x;
    if (t < FPB) fh[t] = 0;
    __syncthreads();
    const int* pbase = S.pairs + (size_t)bucket * GCAP;
    int cnt = min(S.cur[bucket], GCAP);
    for (int i2 = t; i2 < cnt; i2 += 256)
        atomicAdd(&fh[pbase[i2] & FMASK], 1);
    __syncthreads();
    if (t < FPB) sc[t] = fh[t];
    __syncthreads();
    for (int off = 1; off < FPB; off <<= 1) {
        int v = 0;
        if (t < FPB) v = sc[t] + ((t >= off) ? sc[t - off] : 0);
        __syncthreads();
        if (t < FPB) sc[t] = v;
        __syncthreads();
    }
    if (t < FPB) { foff[t] = sc[t] - fh[t]; fcur[t] = sc[t] - fh[t]; }
    __syncthreads();
    for (int i2 = t; i2 < cnt; i2 += 256) {
        int v = pbase[i2];
        int r = atomicAdd(&fcur[v & FMASK], 1);
        fsrc[r] = v >> SHIFT;
    }
    // rank rows by degree (descending; ties by index)
    if (t < FPB) {
        int c = fh[t];
        int r = 0;
        for (int j = 0; j < FPB; ++j) {
            int cj = fh[j];
            r += (cj > c) || (cj == c && j < t);
        }
        rmap[r] = (unsigned char)t;
    }
    __syncthreads();

    int g = t >> 4, sub = t & 15;
    int base_d = bucket << SHIFT;

    for (int pass = 0; pass < 2; ++pass) {
        int r0 = pass == 0 ? 2 * g     : 62 - 2 * g;
        int r1 = pass == 0 ? 2 * g + 1 : 63 - 2 * g;

#define DECL_CHAIN(J)                                                          \
        int row##J = rmap[r##J];                                               \
        int d##J = base_d + row##J;                                            \
        bool ok##J = d##J < S.n_dst;                                           \
        int s0##J = foff[row##J];                                              \
        int cf##J = ok##J ? fh[row##J] : 0;                                    \
        float4 bv##J = ok##J ? load_dst<H>(S, d##J, sub)                       \
                             : make_float4(0.f, 0.f, 0.f, 0.f);                \
        float ss##J = 0.0f;                                                    \
        float4 acc##J = make_float4(0.f, 0.f, 0.f, 0.f);                       \
        Raw rA##J{}, rB##J{}, rC##J{}, rD##J{};                                \
        if (cf##J > 0) rA##J = raw_load<H>(S, fsrc[s0##J + 0], sub);           \
        if (cf##J > 1) rB##J = raw_load<H>(S, fsrc[s0##J + 1], sub);           \
        if (cf##J > 2) rC##J = raw_load<H>(S, fsrc[s0##J + 2], sub);           \
        if (cf##J > 3) rD##J = raw_load<H>(S, fsrc[s0##J + 3], sub);

        DECL_CHAIN(0) DECL_CHAIN(1)

#define STEP(J, RV, KK)                                                        \
            if ((KK) < cf##J) {                                                \
                float4 AV = to_f4<H>(RV);                                      \
                float p = AV.x * bv##J.x + AV.y * bv##J.y +                    \
                          AV.z * bv##J.z + AV.w * bv##J.w;                     \
                p = row16_allsum(p);                                           \
                p = fmaxf(p, NEG_SLOPE * p);   /* leaky relu, branch-free */   \
                float w = __expf(fminf(p, 85.0f));                             \
                ss##J += w;                                                    \
                acc##J.x += w * AV.x; acc##J.y += w * AV.y;                    \
                acc##J.z += w * AV.z; acc##J.w += w * AV.w;                    \
            }

        int kmax = max(cf0, cf1);
        for (int k = 0; k < kmax; k += 4) {
            // issue next 4 gathers per chain (raw, no cvt) before consuming
            Raw nA0{}, nB0{}, nC0{}, nD0{}, nA1{}, nB1{}, nC1{}, nD1{};
            if (k + 4 < cf0) nA0 = raw_load<H>(S, fsrc[s00 + k + 4], sub);
            if (k + 5 < cf0) nB0 = raw_load<H>(S, fsrc[s00 + k + 5], sub);
            if (k + 6 < cf0) nC0 = raw_load<H>(S, fsrc[s00 + k + 6], sub);
            if (k + 7 < cf0) nD0 = raw_load<H>(S, fsrc[s00 + k + 7], sub);
            if (k + 4 < cf1) nA1 = raw_load<H>(S, fsrc[s01 + k + 4], sub);
            if (k + 5 < cf1) nB1 = raw_load<H>(S, fsrc[s01 + k + 5], sub);
            if (k + 6 < cf1) nC1 = raw_load<H>(S, fsrc[s01 + k + 6], sub);
            if (k + 7 < cf1) nD1 = raw_load<H>(S, fsrc[s01 + k + 7], sub);

            STEP(0, rA0, k)     STEP(1, rA1, k)
            STEP(0, rB0, k + 1) STEP(1, rB1, k + 1)
            STEP(0, rC0, k + 2) STEP(1, rC1, k + 2)
            STEP(0, rD0, k + 3) STEP(1, rD1, k + 3)

            rA0 = nA0; rB0 = nB0; rC0 = nC0; rD0 = nD0;
            rA1 = nA1; rB1 = nB1; rC1 = nC1; rD1 = nD1;
        }

#define STORE_CHAIN(J)                                                         \
        if (ok##J) {                                                           \
            float inv = (ss##J > 0.0f) ? 1.0f / ss##J : 0.0f;                  \
            *reinterpret_cast<float4*>(                                        \
                S.out + (size_t)d##J * EMB_DIM + sub * 4) =                    \
                make_float4(acc##J.x * inv, acc##J.y * inv,                    \
                            acc##J.z * inv, acc##J.w * inv);                   \
        }
        STORE_CHAIN(0) STORE_CHAIN(1)
    }
}

// ---------- host orchestration ----------------------------------------------
extern "C" void kernel_launch(void* const* d_in, const int* in_sizes, int n_in,
                              void* d_out, int out_size, void* d_ws, size_t ws_size,
                              hipStream_t stream) {
    const float* user_emb = (const float*)d_in[0];
    const float* item_emb = (const float*)d_in[1];
    const int* ui_src = (const int*)d_in[2];
    const int* ui_dst = (const int*)d_in[3];
    const int* iu_src = (const int*)d_in[4];
    const int* iu_dst = (const int*)d_in[5];

    float* out = (float*)d_out;
    float* item_out = out;                              // [N_ITEM, 64]
    float* user_out = out + (size_t)N_ITEM * EMB_DIM;   // [N_USER, 64]

    const int E0 = in_sizes[2];
    const int E1 = in_sizes[4];

    Side A, B;
    A.srcf = user_emb; A.dstf = item_emb; A.src = ui_src; A.dst = ui_dst;
    A.E = E0; A.n_dst = N_ITEM; A.out = item_out; A.srch = nullptr; A.dsth = nullptr;
    B.srcf = item_emb; B.dstf = user_emb; B.src = iu_src; B.dst = iu_dst;
    B.E = E1; B.n_dst = N_USER; B.out = user_out; B.srch = nullptr; B.dsth = nullptr;

    const size_t half_elems  = (size_t)(N_USER + N_ITEM) * EMB_DIM;
    const size_t half_bytes  = half_elems * sizeof(__half);          // 25.6 MB
    const size_t pairs_bytes = (size_t)NB * GCAP * 4;                // 6.4 MB/side
    const size_t cur_bytes   = (size_t)NB * 4;
    const size_t need_fixed32 = 2 * (pairs_bytes + cur_bytes);       // ~12.8 MB
    const size_t need_fixed16 = need_fixed32 + half_bytes;           // ~38.4 MB

    const bool use_fp16 = ws_size >= need_fixed16;
    char* wsb = (char*)d_ws;
    __half* hu = nullptr; __half* hi = nullptr;
    if (use_fp16) {
        hu = (__half*)wsb;
        hi = hu + (size_t)N_USER * EMB_DIM;
        wsb += half_bytes;
        A.srch = hu; A.dsth = hi;   // A: gathers user rows, dst = item rows
        B.srch = hi; B.dsth = hu;   // B: gathers item rows, dst = user rows
    }
    A.cur   = (int*)wsb;
    B.cur   = A.cur + NB;
    A.pairs = B.cur + NB;
    B.pairs = A.pairs + (size_t)NB * GCAP;

    // zero cursors only (pairs slots in use are fully overwritten)
    hipMemsetAsync(A.cur, 0, 2 * cur_bytes, stream);

    const int nbinA = (E0 + BIN_TILE - 1) / BIN_TILE;
    const int nbinB = (E1 + BIN_TILE - 1) / BIN_TILE;
    const int cvt_blocks = use_fp16 ? (int)(half_elems / 4 / 512) : 0;  // 6250

    prep_kernel<<<nbinA + nbinB + cvt_blocks, 512, 0, stream>>>(
        A, B, nbinA, nbinB,
        use_fp16 ? user_emb : nullptr, use_fp16 ? item_emb : nullptr, hu, hi);

    // XCD-partitioned grid: 8 * ceil(NB/4); blocks with out-of-range ordinals
    // return immediately (<=8 idle blocks).
    const int gat_grid = 8 * ((NB + 3) / 4);
    if (use_fp16) gat_kernel<true><<<gat_grid, 256, 0, stream>>>(A, B, NB);
    else          gat_kernel<false><<<gat_grid, 256, 0, stream>>>(A, B, NB);
}